// Round 10
// baseline (120.886 us; speedup 1.0000x reference)
//
#include <hip/hip_runtime.h>
#include <hip/hip_bf16.h>

#define NROW 4096
#define KDIM 2048
#define ROWB (KDIM * 2)     // bytes per Xb row
#define BT 128              // block tile (M = N)
#define NBJ (NROW / BT)     // 32 block-cols
#define BK 32               // k-tile depth (64 bytes)
#define NT (KDIM / BK)      // 64 k-tiles
#define KTBUF 16384         // per k-tile: A 8 KB + B 8 KB
#define AB_OFF 8192
#define PHI(r) ((((r) >> 1) & 3) << 4)   // verified 0 bank conflicts (r3/r8/r9)

typedef __attribute__((ext_vector_type(8))) short bf16x8;
typedef __attribute__((ext_vector_type(4))) float f32x4;
typedef __attribute__((ext_vector_type(4))) unsigned short u16x4;

#define MFMA16(a, b, c) __builtin_amdgcn_mfma_f32_16x16x32_bf16((a), (b), (c), 0, 0, 0)

__device__ __forceinline__ unsigned short f2bf(float x) {
    unsigned u = __float_as_uint(x);
    unsigned r = (u + 0x7FFFu + ((u >> 16) & 1u)) >> 16;
    return (unsigned short)r;
}
__device__ __forceinline__ float bf2f(unsigned short b) {
    return __uint_as_float(((unsigned)b) << 16);
}

// Kernel 1: fp32 -> bf16 copy + row sum-of-squares from the bf16 values.
// Also folds the accumulator-init (first 16 blocks) and out-zeroing.
__global__ __launch_bounds__(256) void k_convert(const float* __restrict__ X,
                                                 unsigned short* __restrict__ Xb,
                                                 float* __restrict__ sqv,
                                                 unsigned* __restrict__ hp,
                                                 unsigned* __restrict__ hn,
                                                 unsigned* __restrict__ mor,
                                                 unsigned* __restrict__ mir,
                                                 float* __restrict__ out) {
    const int row = blockIdx.x;
    const int t = threadIdx.x;
    if (row < 16) {  // init per-row accumulators (d^2-space)
        const int i = row * 256 + t;
        hp[i] = 0u;
        hn[i] = 0x7F800000u;
        mor[i] = 0u;
        mir[i] = 0x7F800000u;
        if (i == 0) out[0] = 0.f;
    }
    const float4* xr = (const float4*)(X + (size_t)row * KDIM);
    unsigned short* br = Xb + (size_t)row * KDIM;
    float acc = 0.f;
#pragma unroll
    for (int it = 0; it < 2; ++it) {
        int idx = t * 2 + it;
        float4 v = xr[idx];
        u16x4 b;
        b.x = f2bf(v.x); b.y = f2bf(v.y); b.z = f2bf(v.z); b.w = f2bf(v.w);
        float f0 = bf2f(b.x), f1 = bf2f(b.y), f2 = bf2f(b.z), f3 = bf2f(b.w);
        acc += f0 * f0 + f1 * f1 + f2 * f2 + f3 * f3;
        *(u16x4*)(br + idx * 4) = b;
    }
#pragma unroll
    for (int s = 32; s > 0; s >>= 1) acc += __shfl_xor(acc, s);
    __shared__ float red[4];
    const int lane = t & 63, wid = t >> 6;
    if (lane == 0) red[wid] = acc;
    __syncthreads();
    if (t == 0) sqv[row] = red[0] + red[1] + red[2] + red[3];
}

// Kernel 2: 128x128-tile Gram GEMM, FULL 1024-block grid (m97 occupancy
// regime: 3 resident blocks/CU + queue so co-resident blocks hide each
// other's barrier/vmcnt stalls), XCD-aware block swizzle (T1, bijective:
// 1024 % 8 == 0) for A-panel L2 locality. Minimal-sync K-step (round 8):
//   [vmcnt(4); s_barrier; 8 ds_read_b128; stage t+2; 16 MFMA]
// 3 LDS buffers (48 KiB), staging 2 tiles ahead, vmcnt never drains
// mid-loop. Reads issued before the LDS-writing gload_lds of the region.
// Source-side XOR swizzle (rule #21). Epilogue reduces in d^2 space.
__global__ __launch_bounds__(256, 3) void k_gemm(const unsigned short* __restrict__ Xb,
                                                 const float* __restrict__ sqv,
                                                 const int* __restrict__ ta,
                                                 const int* __restrict__ tb,
                                                 unsigned int* __restrict__ hp,
                                                 unsigned int* __restrict__ hn,
                                                 unsigned int* __restrict__ mor,
                                                 unsigned int* __restrict__ mir) {
    __shared__ char lds[3 * KTBUF];  // 48 KiB
    // XCD swizzle: hardware id h (round-robin over 8 XCDs) -> contiguous
    // 128-block chunk per XCD = 4 consecutive bi-panels stay in one L2.
    const int h = blockIdx.x;
    const int o = (h & 7) * 128 + (h >> 3);
    const int bi = o >> 5;
    const int bj = o & 31;

    const int t = threadIdx.x;
    const int lane = t & 63;
    const int w = t >> 6;        // wave 0..3
    const int wm = w >> 1;       // 0..1  (64-row half of A)
    const int wn = w & 1;        // 0..1  (64-col half of B)
    const int l15 = lane & 15;
    const int kg16 = (lane >> 4) * 16;  // k-group 16B slot within 64B row
    const char* xbase = (const char*)Xb;

    // swizzle is lane-constant for frag rows (offsets are multiples of 16)
    const int swz = ((l15 >> 1) & 3) << 4;
    const int akbase = (wm * 64 + l15) * 64 + (kg16 ^ swz);
    const int bkbase = AB_OFF + (wn * 64 + l15) * 64 + (kg16 ^ swz);

    f32x4 acc[4][4] = {};

    // Stage k-tile tt into buffer sb3: 4 gload_lds per thread (A q0,q1 +
    // B q0,q1). Wave-linear LDS dest; swizzle on the global source column.
#define STAGE(tt, sb3)                                                        \
    do {                                                                      \
        _Pragma("unroll")                                                     \
        for (int isb_ = 0; isb_ < 2; ++isb_) {                                \
            _Pragma("unroll")                                                 \
            for (int q_ = 0; q_ < 2; ++q_) {                                  \
                const int row_ = q_ * 64 + (t >> 2);                          \
                const int gr_ = (isb_ ? bj : bi) * BT + row_;                 \
                const char* gsrc_ = xbase + (size_t)gr_ * ROWB +              \
                                    (size_t)(tt) * 64 +                       \
                                    (((t & 3) * 16) ^ PHI(row_));             \
                char* ldst_ = lds + (sb3) * KTBUF + isb_ * AB_OFF +           \
                              row_ * 64 + (t & 3) * 16;                       \
                __builtin_amdgcn_global_load_lds(                             \
                    (const __attribute__((address_space(1))) void*)gsrc_,     \
                    (__attribute__((address_space(3))) void*)ldst_, 16, 0, 0);\
            }                                                                 \
        }                                                                     \
    } while (0)

    // prologue: tiles 0 -> buf0, 1 -> buf1 (8 loads/thread outstanding)
    STAGE(0, 0);
    STAGE(1, 1);

    int r3 = 0, s3 = 2;  // read buffer, stage buffer (t+2)
    for (int tk = 0; tk < NT; ++tk) {
        if (tk < NT - 1)
            asm volatile("s_waitcnt vmcnt(4)" ::: "memory");  // buf r3 resident
        else
            asm volatile("s_waitcnt vmcnt(0)" ::: "memory");
        __builtin_amdgcn_s_barrier();

        const char* buf = lds + r3 * KTBUF;
        // ---- all fragment reads first (before any LDS-writing vmem)
        bf16x8 af[4], bfr[4];
#pragma unroll
        for (int m = 0; m < 4; ++m)
            af[m] = *(const bf16x8*)(buf + akbase + m * 1024);
#pragma unroll
        for (int n = 0; n < 4; ++n)
            bfr[n] = *(const bf16x8*)(buf + bkbase + n * 1024);

        // ---- stage tile tk+2 (WAR-safe: that buffer's reads finished
        // before the barrier above)
        if (tk + 2 < NT) STAGE(tk + 2, s3);

        // ---- 16 MFMA; compiler inserts fine-grained lgkm waits
#pragma unroll
        for (int m = 0; m < 4; ++m)
#pragma unroll
            for (int n = 0; n < 4; ++n)
                acc[m][n] = MFMA16(af[m], bfr[n], acc[m][n]);

        r3 = (r3 == 2) ? 0 : r3 + 1;
        s3 = (s3 == 2) ? 0 : s3 + 1;
    }
#undef STAGE

    // ---- epilogue: d^2 + masks + row-side reductions (d^2-space) ----
    float sqj[4];
    int taj[4], tbj[4];
#pragma unroll
    for (int n = 0; n < 4; ++n) {
        int j = bj * BT + wn * 64 + n * 16 + l15;
        sqj[n] = sqv[j];
        taj[n] = ta[j];
        tbj[n] = tb[j];
    }
    const float INF = __uint_as_float(0x7F800000u);
#pragma unroll
    for (int m = 0; m < 4; ++m) {
#pragma unroll
        for (int reg = 0; reg < 4; ++reg) {
            const int i = bi * BT + wm * 64 + m * 16 + (lane >> 4) * 4 + reg;
            const float sqi = sqv[i];
            const int tai = ta[i], tbi = tb[i];
            float vhp = 0.f, vhn = INF, vmo = 0.f, vmi = INF;
#pragma unroll
            for (int n = 0; n < 4; ++n) {
                float d2 = fmaxf(sqi + sqj[n] - 2.f * acc[m][n][reg], 1e-12f);
                bool ma = (tai == taj[n]), mb = (tbi == tbj[n]);
                if (ma && mb) {
                    vhp = fmaxf(vhp, d2);
                } else if (ma != mb) {
                    vmo = fmaxf(vmo, d2);
                    vmi = fminf(vmi, d2);
                } else {
                    vhn = fminf(vhn, d2);
                }
            }
#pragma unroll
            for (int s = 1; s < 16; s <<= 1) {
                vhp = fmaxf(vhp, __shfl_xor(vhp, s, 16));
                vhn = fminf(vhn, __shfl_xor(vhn, s, 16));
                vmo = fmaxf(vmo, __shfl_xor(vmo, s, 16));
                vmi = fminf(vmi, __shfl_xor(vmi, s, 16));
            }
            if (l15 == 0) {
                if (vhp > 0.f) atomicMax(&hp[i], __float_as_uint(vhp));
                if (vhn < INF) atomicMin(&hn[i], __float_as_uint(vhn));
                if (vmo > 0.f) {
                    atomicMax(&mor[i], __float_as_uint(vmo));
                    atomicMin(&mir[i], __float_as_uint(vmi));
                }
            }
        }
    }
}

// Kernel 3: final scalar loss (sqrt applied here; mor!=0 is the or-flag).
__global__ __launch_bounds__(256) void k_final(const unsigned* __restrict__ hp,
                                               const unsigned* __restrict__ hn,
                                               const unsigned* __restrict__ mor,
                                               const unsigned* __restrict__ mir,
                                               const int* __restrict__ epoch_p,
                                               float* __restrict__ out) {
    const int t = threadIdx.x;
    const int i = blockIdx.x * 256 + t;
    const bool eok = (*epoch_p > 50);
    const unsigned morb = mor[i];
    float fhp = sqrtf(__uint_as_float(hp[i]));
    float fhn = sqrtf(__uint_as_float(hn[i]));
    bool use_or = (morb != 0u) && eok;
    float sp = use_or ? sqrtf(__uint_as_float(morb)) : fhp;
    float sn = use_or ? sqrtf(__uint_as_float(mir[i])) : fhn;
    float s = fmaxf(0.f, fhp - fhn + 0.3f) + fmaxf(0.f, sp - fhn + 0.3f) +
              fmaxf(0.f, fhp - sn + 0.3f);
#pragma unroll
    for (int sh = 32; sh > 0; sh >>= 1) s += __shfl_xor(s, sh);
    __shared__ float red[4];
    const int lane = t & 63, wid = t >> 6;
    if (lane == 0) red[wid] = s;
    __syncthreads();
    if (t == 0)
        atomicAdd(out, (red[0] + red[1] + red[2] + red[3]) * (1.f / 4096.f));
}

extern "C" void kernel_launch(void* const* d_in, const int* in_sizes, int n_in,
                              void* d_out, int out_size, void* d_ws, size_t ws_size,
                              hipStream_t stream) {
    const float* X = (const float*)d_in[0];
    const int* ta = (const int*)d_in[1];
    const int* tb = (const int*)d_in[2];
    const int* epoch_p = (const int*)d_in[4];
    float* out = (float*)d_out;

    char* ws = (char*)d_ws;
    unsigned short* Xb = (unsigned short*)ws;  // 16 MB bf16 copy
    size_t off = (size_t)NROW * KDIM * sizeof(unsigned short);
    float* sqv = (float*)(ws + off); off += (size_t)NROW * 4;
    unsigned* hp = (unsigned*)(ws + off); off += (size_t)NROW * 4;
    unsigned* hn = (unsigned*)(ws + off); off += (size_t)NROW * 4;
    unsigned* mor = (unsigned*)(ws + off); off += (size_t)NROW * 4;
    unsigned* mir = (unsigned*)(ws + off); off += (size_t)NROW * 4;

    k_convert<<<NROW, 256, 0, stream>>>(X, Xb, sqv, hp, hn, mor, mir, out);
    k_gemm<<<(NROW / BT) * (NROW / BT), 256, 0, stream>>>(Xb, sqv, ta, tb,
                                                          hp, hn, mor, mir);
    k_final<<<NROW / 256, 256, 0, stream>>>(hp, hn, mor, mir, epoch_p, out);
}

// Round 11
// 114.888 us; speedup vs baseline: 1.0522x; 1.0522x over previous
//
#include <hip/hip_runtime.h>
#include <hip/hip_bf16.h>

#define NROW 4096
#define KDIM 2048
#define ROWB (KDIM * 2)     // bytes per Xb row
#define BT 128              // block tile (M = N)
#define NBJ (NROW / BT)     // 32 block-cols
#define BK 32               // k-tile depth (64 bytes)
#define NT (KDIM / BK)      // 64 k-tiles
#define KTBUF 16384         // per k-tile: A 8 KB + B 8 KB
#define AB_OFF 8192
#define PHI(r) ((((r) >> 1) & 3) << 4)   // verified 0 bank conflicts (r3/r8/r9)

typedef __attribute__((ext_vector_type(8))) short bf16x8;
typedef __attribute__((ext_vector_type(4))) float f32x4;
typedef __attribute__((ext_vector_type(4))) unsigned short u16x4;

#define MFMA16(a, b, c) __builtin_amdgcn_mfma_f32_16x16x32_bf16((a), (b), (c), 0, 0, 0)

__device__ __forceinline__ unsigned short f2bf(float x) {
    unsigned u = __float_as_uint(x);
    unsigned r = (u + 0x7FFFu + ((u >> 16) & 1u)) >> 16;
    return (unsigned short)r;
}
__device__ __forceinline__ float bf2f(unsigned short b) {
    return __uint_as_float(((unsigned)b) << 16);
}

// Kernel 1: fp32 -> bf16 copy + row sum-of-squares from the bf16 values.
// Also folds the accumulator-init (first 16 blocks) and out-zeroing.
__global__ __launch_bounds__(256) void k_convert(const float* __restrict__ X,
                                                 unsigned short* __restrict__ Xb,
                                                 float* __restrict__ sqv,
                                                 unsigned* __restrict__ hp,
                                                 unsigned* __restrict__ hn,
                                                 unsigned* __restrict__ mor,
                                                 unsigned* __restrict__ mir,
                                                 float* __restrict__ out) {
    const int row = blockIdx.x;
    const int t = threadIdx.x;
    if (row < 16) {  // init per-row accumulators (d^2-space)
        const int i = row * 256 + t;
        hp[i] = 0u;
        hn[i] = 0x7F800000u;
        mor[i] = 0u;
        mir[i] = 0x7F800000u;
        if (i == 0) out[0] = 0.f;
    }
    const float4* xr = (const float4*)(X + (size_t)row * KDIM);
    unsigned short* br = Xb + (size_t)row * KDIM;
    float acc = 0.f;
#pragma unroll
    for (int it = 0; it < 2; ++it) {
        int idx = t * 2 + it;
        float4 v = xr[idx];
        u16x4 b;
        b.x = f2bf(v.x); b.y = f2bf(v.y); b.z = f2bf(v.z); b.w = f2bf(v.w);
        float f0 = bf2f(b.x), f1 = bf2f(b.y), f2 = bf2f(b.z), f3 = bf2f(b.w);
        acc += f0 * f0 + f1 * f1 + f2 * f2 + f3 * f3;
        *(u16x4*)(br + idx * 4) = b;
    }
#pragma unroll
    for (int s = 32; s > 0; s >>= 1) acc += __shfl_xor(acc, s);
    __shared__ float red[4];
    const int lane = t & 63, wid = t >> 6;
    if (lane == 0) red[wid] = acc;
    __syncthreads();
    if (t == 0) sqv[row] = red[0] + red[1] + red[2] + red[3];
}

// Kernel 2: 128x128-tile Gram GEMM, FULL 1024-block grid in NATURAL order
// (consecutive blocks share the A panel in L2; input is L2-aggregate-
// resident, 16 MB -- R10's XCD swizzle tripled FETCH_SIZE and regressed).
// 48 KiB LDS -> 3 resident blocks/CU + ~256-block queue (m97 regime);
// co-resident blocks hide each other's barrier/vmcnt stalls (m114).
// Minimal-sync K-step (round 8):
//   [vmcnt(4); s_barrier; 8 ds_read_b128; stage t+2; 16 MFMA]
// Reads issued before the LDS-writing gload_lds of the region. Source-side
// XOR swizzle (rule #21). Epilogue reduces in d^2 space (sqrt deferred).
__global__ __launch_bounds__(256, 3) void k_gemm(const unsigned short* __restrict__ Xb,
                                                 const float* __restrict__ sqv,
                                                 const int* __restrict__ ta,
                                                 const int* __restrict__ tb,
                                                 unsigned int* __restrict__ hp,
                                                 unsigned int* __restrict__ hn,
                                                 unsigned int* __restrict__ mor,
                                                 unsigned int* __restrict__ mir) {
    __shared__ char lds[3 * KTBUF];  // 48 KiB
    const int bi = blockIdx.x >> 5;
    const int bj = blockIdx.x & 31;

    const int t = threadIdx.x;
    const int lane = t & 63;
    const int w = t >> 6;        // wave 0..3
    const int wm = w >> 1;       // 0..1  (64-row half of A)
    const int wn = w & 1;        // 0..1  (64-col half of B)
    const int l15 = lane & 15;
    const int kg16 = (lane >> 4) * 16;  // k-group 16B slot within 64B row
    const char* xbase = (const char*)Xb;

    // swizzle is lane-constant for frag rows (offsets are multiples of 16)
    const int swz = ((l15 >> 1) & 3) << 4;
    const int akbase = (wm * 64 + l15) * 64 + (kg16 ^ swz);
    const int bkbase = AB_OFF + (wn * 64 + l15) * 64 + (kg16 ^ swz);

    f32x4 acc[4][4] = {};

    // Stage k-tile tt into buffer sb3: 4 gload_lds per thread (A q0,q1 +
    // B q0,q1). Wave-linear LDS dest; swizzle on the global source column.
#define STAGE(tt, sb3)                                                        \
    do {                                                                      \
        _Pragma("unroll")                                                     \
        for (int isb_ = 0; isb_ < 2; ++isb_) {                                \
            _Pragma("unroll")                                                 \
            for (int q_ = 0; q_ < 2; ++q_) {                                  \
                const int row_ = q_ * 64 + (t >> 2);                          \
                const int gr_ = (isb_ ? bj : bi) * BT + row_;                 \
                const char* gsrc_ = xbase + (size_t)gr_ * ROWB +              \
                                    (size_t)(tt) * 64 +                       \
                                    (((t & 3) * 16) ^ PHI(row_));             \
                char* ldst_ = lds + (sb3) * KTBUF + isb_ * AB_OFF +           \
                              row_ * 64 + (t & 3) * 16;                       \
                __builtin_amdgcn_global_load_lds(                             \
                    (const __attribute__((address_space(1))) void*)gsrc_,     \
                    (__attribute__((address_space(3))) void*)ldst_, 16, 0, 0);\
            }                                                                 \
        }                                                                     \
    } while (0)

    // prologue: tiles 0 -> buf0, 1 -> buf1 (8 loads/thread outstanding)
    STAGE(0, 0);
    STAGE(1, 1);

    int r3 = 0, s3 = 2;  // read buffer, stage buffer (t+2)
    for (int tk = 0; tk < NT; ++tk) {
        if (tk < NT - 1)
            asm volatile("s_waitcnt vmcnt(4)" ::: "memory");  // buf r3 resident
        else
            asm volatile("s_waitcnt vmcnt(0)" ::: "memory");
        __builtin_amdgcn_s_barrier();

        const char* buf = lds + r3 * KTBUF;
        // ---- all fragment reads first (before any LDS-writing vmem)
        bf16x8 af[4], bfr[4];
#pragma unroll
        for (int m = 0; m < 4; ++m)
            af[m] = *(const bf16x8*)(buf + akbase + m * 1024);
#pragma unroll
        for (int n = 0; n < 4; ++n)
            bfr[n] = *(const bf16x8*)(buf + bkbase + n * 1024);

        // ---- stage tile tk+2 (WAR-safe: that buffer's reads finished
        // before the barrier above)
        if (tk + 2 < NT) STAGE(tk + 2, s3);

        // ---- 16 MFMA; compiler inserts fine-grained lgkm waits
#pragma unroll
        for (int m = 0; m < 4; ++m)
#pragma unroll
            for (int n = 0; n < 4; ++n)
                acc[m][n] = MFMA16(af[m], bfr[n], acc[m][n]);

        r3 = (r3 == 2) ? 0 : r3 + 1;
        s3 = (s3 == 2) ? 0 : s3 + 1;
    }
#undef STAGE

    // ---- epilogue: d^2 + masks + row-side reductions (d^2-space) ----
    float sqj[4];
    int taj[4], tbj[4];
#pragma unroll
    for (int n = 0; n < 4; ++n) {
        int j = bj * BT + wn * 64 + n * 16 + l15;
        sqj[n] = sqv[j];
        taj[n] = ta[j];
        tbj[n] = tb[j];
    }
    const float INF = __uint_as_float(0x7F800000u);
#pragma unroll
    for (int m = 0; m < 4; ++m) {
#pragma unroll
        for (int reg = 0; reg < 4; ++reg) {
            const int i = bi * BT + wm * 64 + m * 16 + (lane >> 4) * 4 + reg;
            const float sqi = sqv[i];
            const int tai = ta[i], tbi = tb[i];
            float vhp = 0.f, vhn = INF, vmo = 0.f, vmi = INF;
#pragma unroll
            for (int n = 0; n < 4; ++n) {
                float d2 = fmaxf(sqi + sqj[n] - 2.f * acc[m][n][reg], 1e-12f);
                bool ma = (tai == taj[n]), mb = (tbi == tbj[n]);
                if (ma && mb) {
                    vhp = fmaxf(vhp, d2);
                } else if (ma != mb) {
                    vmo = fmaxf(vmo, d2);
                    vmi = fminf(vmi, d2);
                } else {
                    vhn = fminf(vhn, d2);
                }
            }
#pragma unroll
            for (int s = 1; s < 16; s <<= 1) {
                vhp = fmaxf(vhp, __shfl_xor(vhp, s, 16));
                vhn = fminf(vhn, __shfl_xor(vhn, s, 16));
                vmo = fmaxf(vmo, __shfl_xor(vmo, s, 16));
                vmi = fminf(vmi, __shfl_xor(vmi, s, 16));
            }
            if (l15 == 0) {
                if (vhp > 0.f) atomicMax(&hp[i], __float_as_uint(vhp));
                if (vhn < INF) atomicMin(&hn[i], __float_as_uint(vhn));
                if (vmo > 0.f) {
                    atomicMax(&mor[i], __float_as_uint(vmo));
                    atomicMin(&mir[i], __float_as_uint(vmi));
                }
            }
        }
    }
}

// Kernel 3: final scalar loss (sqrt applied here; mor!=0 is the or-flag).
__global__ __launch_bounds__(256) void k_final(const unsigned* __restrict__ hp,
                                               const unsigned* __restrict__ hn,
                                               const unsigned* __restrict__ mor,
                                               const unsigned* __restrict__ mir,
                                               const int* __restrict__ epoch_p,
                                               float* __restrict__ out) {
    const int t = threadIdx.x;
    const int i = blockIdx.x * 256 + t;
    const bool eok = (*epoch_p > 50);
    const unsigned morb = mor[i];
    float fhp = sqrtf(__uint_as_float(hp[i]));
    float fhn = sqrtf(__uint_as_float(hn[i]));
    bool use_or = (morb != 0u) && eok;
    float sp = use_or ? sqrtf(__uint_as_float(morb)) : fhp;
    float sn = use_or ? sqrtf(__uint_as_float(mir[i])) : fhn;
    float s = fmaxf(0.f, fhp - fhn + 0.3f) + fmaxf(0.f, sp - fhn + 0.3f) +
              fmaxf(0.f, fhp - sn + 0.3f);
#pragma unroll
    for (int sh = 32; sh > 0; sh >>= 1) s += __shfl_xor(s, sh);
    __shared__ float red[4];
    const int lane = t & 63, wid = t >> 6;
    if (lane == 0) red[wid] = s;
    __syncthreads();
    if (t == 0)
        atomicAdd(out, (red[0] + red[1] + red[2] + red[3]) * (1.f / 4096.f));
}

extern "C" void kernel_launch(void* const* d_in, const int* in_sizes, int n_in,
                              void* d_out, int out_size, void* d_ws, size_t ws_size,
                              hipStream_t stream) {
    const float* X = (const float*)d_in[0];
    const int* ta = (const int*)d_in[1];
    const int* tb = (const int*)d_in[2];
    const int* epoch_p = (const int*)d_in[4];
    float* out = (float*)d_out;

    char* ws = (char*)d_ws;
    unsigned short* Xb = (unsigned short*)ws;  // 16 MB bf16 copy
    size_t off = (size_t)NROW * KDIM * sizeof(unsigned short);
    float* sqv = (float*)(ws + off); off += (size_t)NROW * 4;
    unsigned* hp = (unsigned*)(ws + off); off += (size_t)NROW * 4;
    unsigned* hn = (unsigned*)(ws + off); off += (size_t)NROW * 4;
    unsigned* mor = (unsigned*)(ws + off); off += (size_t)NROW * 4;
    unsigned* mir = (unsigned*)(ws + off); off += (size_t)NROW * 4;

    k_convert<<<NROW, 256, 0, stream>>>(X, Xb, sqv, hp, hn, mor, mir, out);
    k_gemm<<<(NROW / BT) * (NROW / BT), 256, 0, stream>>>(Xb, sqv, ta, tb,
                                                          hp, hn, mor, mir);
    k_final<<<NROW / 256, 256, 0, stream>>>(hp, hn, mor, mir, epoch_p, out);
}

// Round 12
// 97.055 us; speedup vs baseline: 1.2455x; 1.1837x over previous
//
#include <hip/hip_runtime.h>
#include <hip/hip_bf16.h>

#define NROW 4096
#define KDIM 2048
#define ROWB (KDIM * 2)     // bytes per Xb row
#define BT 128              // block tile (M = N)
#define NB (NROW / BT)      // 32 block-rows; triangle grid = 528
#define BK 32               // k-tile depth (64 bytes)
#define NT (KDIM / BK)      // 64 k-tiles
#define KTBUF 16384         // per k-tile: A 8 KB + B 8 KB
#define AB_OFF 8192
#define PHI(r) ((((r) >> 1) & 3) << 4)   // verified 0 bank conflicts (r3/r8/r9)

typedef __attribute__((ext_vector_type(8))) short bf16x8;
typedef __attribute__((ext_vector_type(4))) float f32x4;
typedef __attribute__((ext_vector_type(4))) unsigned short u16x4;

#define MFMA16(a, b, c) __builtin_amdgcn_mfma_f32_16x16x32_bf16((a), (b), (c), 0, 0, 0)

__device__ __forceinline__ unsigned short f2bf(float x) {
    unsigned u = __float_as_uint(x);
    unsigned r = (u + 0x7FFFu + ((u >> 16) & 1u)) >> 16;
    return (unsigned short)r;
}
__device__ __forceinline__ float bf2f(unsigned short b) {
    return __uint_as_float(((unsigned)b) << 16);
}

// Kernel 1: fp32 -> bf16 copy + row sum-of-squares from the bf16 values.
// Also folds the accumulator-init (first 16 blocks) and out-zeroing.
__global__ __launch_bounds__(256) void k_convert(const float* __restrict__ X,
                                                 unsigned short* __restrict__ Xb,
                                                 float* __restrict__ sqv,
                                                 unsigned* __restrict__ hp,
                                                 unsigned* __restrict__ hn,
                                                 unsigned* __restrict__ mor,
                                                 unsigned* __restrict__ mir,
                                                 float* __restrict__ out) {
    const int row = blockIdx.x;
    const int t = threadIdx.x;
    if (row < 16) {  // init per-row accumulators (d^2-space)
        const int i = row * 256 + t;
        hp[i] = 0u;
        hn[i] = 0x7F800000u;
        mor[i] = 0u;
        mir[i] = 0x7F800000u;
        if (i == 0) out[0] = 0.f;
    }
    const float4* xr = (const float4*)(X + (size_t)row * KDIM);
    unsigned short* br = Xb + (size_t)row * KDIM;
    float acc = 0.f;
#pragma unroll
    for (int it = 0; it < 2; ++it) {
        int idx = t * 2 + it;
        float4 v = xr[idx];
        u16x4 b;
        b.x = f2bf(v.x); b.y = f2bf(v.y); b.z = f2bf(v.z); b.w = f2bf(v.w);
        float f0 = bf2f(b.x), f1 = bf2f(b.y), f2 = bf2f(b.z), f3 = bf2f(b.w);
        acc += f0 * f0 + f1 * f1 + f2 * f2 + f3 * f3;
        *(u16x4*)(br + idx * 4) = b;
    }
#pragma unroll
    for (int s = 32; s > 0; s >>= 1) acc += __shfl_xor(acc, s);
    __shared__ float red[4];
    const int lane = t & 63, wid = t >> 6;
    if (lane == 0) red[wid] = acc;
    __syncthreads();
    if (t == 0) sqv[row] = red[0] + red[1] + red[2] + red[3];
}

// Kernel 2: 128x128-tile Gram GEMM, UPPER-TRIANGLE grid (528 blocks, half
// the FLOPs; dist/masks symmetric, max/min idempotent), 512 THREADS (8
// waves, 2x4 wave grid) so 2 resident blocks/CU = 16 waves/CU (4/SIMD)
// hide the per-tile vmcnt/barrier stall (R11 showed per-block time is
// 1.5x better at high wave count; R9 showed triangle wins on work).
// Minimal-sync K-step (round 8): [vmcnt(2); s_barrier; 6 ds_read_b128;
// stage t+2 (2 gload_lds); 8 MFMA]. 3 LDS buffers (48 KiB), staging 2
// tiles ahead, vmcnt never drains mid-loop. Natural dispatch order.
// Source-side XOR swizzle (rule #21). Epilogue in d^2 space, row+col side.
__global__ __launch_bounds__(512, 4) void k_gemm(const unsigned short* __restrict__ Xb,
                                                 const float* __restrict__ sqv,
                                                 const int* __restrict__ ta,
                                                 const int* __restrict__ tb,
                                                 unsigned int* __restrict__ hp,
                                                 unsigned int* __restrict__ hn,
                                                 unsigned int* __restrict__ mor,
                                                 unsigned int* __restrict__ mir) {
    __shared__ char lds[3 * KTBUF];  // 48 KiB
    // triangle decode: block-row bi has (NB - bi) blocks, bj in [bi, NB)
    int rem = blockIdx.x;
    int bi = 0;
    while (rem >= NB - bi) { rem -= NB - bi; ++bi; }
    const int bj = bi + rem;

    const int t = threadIdx.x;
    const int lane = t & 63;
    const int w = t >> 6;        // wave 0..7
    const int wm = w >> 2;       // 0..1  (64-row half of A)
    const int wn = w & 3;        // 0..3  (32-col quarter of B)
    const int l15 = lane & 15;
    const int kg16 = (lane >> 4) * 16;  // k-group 16B slot within 64B row
    const char* xbase = (const char*)Xb;

    // swizzle is lane-constant for frag rows (offsets are multiples of 16)
    const int swz = ((l15 >> 1) & 3) << 4;
    const int akbase = (wm * 64 + l15) * 64 + (kg16 ^ swz);
    const int bkbase = AB_OFF + (wn * 32 + l15) * 64 + (kg16 ^ swz);

    f32x4 acc[4][2] = {};

    // Stage k-tile tt into buffer sb3: 2 gload_lds per thread (A, B).
    // 512 threads cover a full 8 KB panel: row t>>2, 16B col t&3.
    // Wave-linear LDS dest; swizzle on the global source column.
#define STAGE(tt, sb3)                                                        \
    do {                                                                      \
        _Pragma("unroll")                                                     \
        for (int isb_ = 0; isb_ < 2; ++isb_) {                                \
            const int row_ = t >> 2;                                          \
            const int gr_ = (isb_ ? bj : bi) * BT + row_;                     \
            const char* gsrc_ = xbase + (size_t)gr_ * ROWB +                  \
                                (size_t)(tt) * 64 +                           \
                                (((t & 3) * 16) ^ PHI(row_));                 \
            char* ldst_ = lds + (sb3) * KTBUF + isb_ * AB_OFF +               \
                          row_ * 64 + (t & 3) * 16;                           \
            __builtin_amdgcn_global_load_lds(                                 \
                (const __attribute__((address_space(1))) void*)gsrc_,         \
                (__attribute__((address_space(3))) void*)ldst_, 16, 0, 0);    \
        }                                                                     \
    } while (0)

    // prologue: tiles 0 -> buf0, 1 -> buf1 (4 loads/thread outstanding)
    STAGE(0, 0);
    STAGE(1, 1);

    int r3 = 0, s3 = 2;  // read buffer, stage buffer (t+2)
    for (int tk = 0; tk < NT; ++tk) {
        if (tk < NT - 1)
            asm volatile("s_waitcnt vmcnt(2)" ::: "memory");  // buf r3 resident
        else
            asm volatile("s_waitcnt vmcnt(0)" ::: "memory");
        __builtin_amdgcn_s_barrier();

        const char* buf = lds + r3 * KTBUF;
        // ---- all fragment reads first (before any LDS-writing vmem)
        bf16x8 af[4], bfr[2];
#pragma unroll
        for (int m = 0; m < 4; ++m)
            af[m] = *(const bf16x8*)(buf + akbase + m * 1024);
#pragma unroll
        for (int n = 0; n < 2; ++n)
            bfr[n] = *(const bf16x8*)(buf + bkbase + n * 1024);

        // ---- stage tile tk+2 (WAR-safe: that buffer's reads finished
        // before the barrier above)
        if (tk + 2 < NT) STAGE(tk + 2, s3);

        // ---- 8 MFMA; compiler inserts fine-grained lgkm waits
#pragma unroll
        for (int m = 0; m < 4; ++m)
#pragma unroll
            for (int n = 0; n < 2; ++n)
                acc[m][n] = MFMA16(af[m], bfr[n], acc[m][n]);

        r3 = (r3 == 2) ? 0 : r3 + 1;
        s3 = (s3 == 2) ? 0 : s3 + 1;
    }
#undef STAGE

    // ---- epilogue: d^2 + masks + row/col reductions (d^2-space) ----
    float sqj[2];
    int taj[2], tbj[2];
#pragma unroll
    for (int n = 0; n < 2; ++n) {
        int j = bj * BT + wn * 32 + n * 16 + l15;
        sqj[n] = sqv[j];
        taj[n] = ta[j];
        tbj[n] = tb[j];
    }
    const float INF = __uint_as_float(0x7F800000u);

    // column-side accumulators (per n, reduced over m/reg in-thread)
    float chp[2], chn[2], cmo[2], cmi[2];
#pragma unroll
    for (int n = 0; n < 2; ++n) {
        chp[n] = 0.f; chn[n] = INF; cmo[n] = 0.f; cmi[n] = INF;
    }

#pragma unroll
    for (int m = 0; m < 4; ++m) {
#pragma unroll
        for (int reg = 0; reg < 4; ++reg) {
            const int i = bi * BT + wm * 64 + m * 16 + (lane >> 4) * 4 + reg;
            const float sqi = sqv[i];
            const int tai = ta[i], tbi = tb[i];
            float vhp = 0.f, vhn = INF, vmo = 0.f, vmi = INF;
#pragma unroll
            for (int n = 0; n < 2; ++n) {
                float d2 = fmaxf(sqi + sqj[n] - 2.f * acc[m][n][reg], 1e-12f);
                bool ma = (tai == taj[n]), mb = (tbi == tbj[n]);
                if (ma && mb) {
                    vhp = fmaxf(vhp, d2);
                    chp[n] = fmaxf(chp[n], d2);
                } else if (ma != mb) {
                    vmo = fmaxf(vmo, d2);
                    vmi = fminf(vmi, d2);
                    cmo[n] = fmaxf(cmo[n], d2);
                    cmi[n] = fminf(cmi[n], d2);
                } else {
                    vhn = fminf(vhn, d2);
                    chn[n] = fminf(chn[n], d2);
                }
            }
#pragma unroll
            for (int s = 1; s < 16; s <<= 1) {
                vhp = fmaxf(vhp, __shfl_xor(vhp, s, 16));
                vhn = fminf(vhn, __shfl_xor(vhn, s, 16));
                vmo = fmaxf(vmo, __shfl_xor(vmo, s, 16));
                vmi = fminf(vmi, __shfl_xor(vmi, s, 16));
            }
            if (l15 == 0) {
                if (vhp > 0.f) atomicMax(&hp[i], __float_as_uint(vhp));
                if (vhn < INF) atomicMin(&hn[i], __float_as_uint(vhn));
                if (vmo > 0.f) {
                    atomicMax(&mor[i], __float_as_uint(vmo));
                    atomicMin(&mir[i], __float_as_uint(vmi));
                }
            }
        }
    }

    if (bi != bj) {
        // column-side: reduce across the 4 row-groups (lane>>4) via xor-16/32
#pragma unroll
        for (int n = 0; n < 2; ++n) {
            float a = chp[n], b = chn[n], c = cmo[n], d = cmi[n];
            a = fmaxf(a, __shfl_xor(a, 16)); a = fmaxf(a, __shfl_xor(a, 32));
            b = fminf(b, __shfl_xor(b, 16)); b = fminf(b, __shfl_xor(b, 32));
            c = fmaxf(c, __shfl_xor(c, 16)); c = fmaxf(c, __shfl_xor(c, 32));
            d = fminf(d, __shfl_xor(d, 16)); d = fminf(d, __shfl_xor(d, 32));
            if (lane < 16) {
                const int j = bj * BT + wn * 32 + n * 16 + lane;
                if (a > 0.f) atomicMax(&hp[j], __float_as_uint(a));
                if (b < INF) atomicMin(&hn[j], __float_as_uint(b));
                if (c > 0.f) {
                    atomicMax(&mor[j], __float_as_uint(c));
                    atomicMin(&mir[j], __float_as_uint(d));
                }
            }
        }
    }
}

// Kernel 3: final scalar loss (sqrt applied here; mor!=0 is the or-flag).
__global__ __launch_bounds__(256) void k_final(const unsigned* __restrict__ hp,
                                               const unsigned* __restrict__ hn,
                                               const unsigned* __restrict__ mor,
                                               const unsigned* __restrict__ mir,
                                               const int* __restrict__ epoch_p,
                                               float* __restrict__ out) {
    const int t = threadIdx.x;
    const int i = blockIdx.x * 256 + t;
    const bool eok = (*epoch_p > 50);
    const unsigned morb = mor[i];
    float fhp = sqrtf(__uint_as_float(hp[i]));
    float fhn = sqrtf(__uint_as_float(hn[i]));
    bool use_or = (morb != 0u) && eok;
    float sp = use_or ? sqrtf(__uint_as_float(morb)) : fhp;
    float sn = use_or ? sqrtf(__uint_as_float(mir[i])) : fhn;
    float s = fmaxf(0.f, fhp - fhn + 0.3f) + fmaxf(0.f, sp - fhn + 0.3f) +
              fmaxf(0.f, fhp - sn + 0.3f);
#pragma unroll
    for (int sh = 32; sh > 0; sh >>= 1) s += __shfl_xor(s, sh);
    __shared__ float red[4];
    const int lane = t & 63, wid = t >> 6;
    if (lane == 0) red[wid] = s;
    __syncthreads();
    if (t == 0)
        atomicAdd(out, (red[0] + red[1] + red[2] + red[3]) * (1.f / 4096.f));
}

extern "C" void kernel_launch(void* const* d_in, const int* in_sizes, int n_in,
                              void* d_out, int out_size, void* d_ws, size_t ws_size,
                              hipStream_t stream) {
    const float* X = (const float*)d_in[0];
    const int* ta = (const int*)d_in[1];
    const int* tb = (const int*)d_in[2];
    const int* epoch_p = (const int*)d_in[4];
    float* out = (float*)d_out;

    char* ws = (char*)d_ws;
    unsigned short* Xb = (unsigned short*)ws;  // 16 MB bf16 copy
    size_t off = (size_t)NROW * KDIM * sizeof(unsigned short);
    float* sqv = (float*)(ws + off); off += (size_t)NROW * 4;
    unsigned* hp = (unsigned*)(ws + off); off += (size_t)NROW * 4;
    unsigned* hn = (unsigned*)(ws + off); off += (size_t)NROW * 4;
    unsigned* mor = (unsigned*)(ws + off); off += (size_t)NROW * 4;
    unsigned* mir = (unsigned*)(ws + off); off += (size_t)NROW * 4;

    k_convert<<<NROW, 256, 0, stream>>>(X, Xb, sqv, hp, hn, mor, mir, out);
    k_gemm<<<(NB * (NB + 1)) / 2, 512, 0, stream>>>(Xb, sqv, ta, tb,
                                                    hp, hn, mor, mir);
    k_final<<<NROW / 256, 256, 0, stream>>>(hp, hn, mor, mir, epoch_p, out);
}